// Round 12
// baseline (121.645 us; speedup 1.0000x reference)
//
#include <hip/hip_runtime.h>

#define NN 100     // N nodes
#define D  128     // d_model
#define BB 128     // batch
#define PP 4950    // pairs

// ws float offsets
#define U_OFF    0
#define V_OFF    (D)                    // 128
#define S_OFF    (V_OFF + NN * D)       // 12928
#define PART_OFF (S_OFF + BB * NN)      // 25728; part[4][BB][D]

__device__ inline void fma4(float4& a, float s, const float4& w) {
    a.x = fmaf(s, w.x, a.x);
    a.y = fmaf(s, w.y, a.y);
    a.z = fmaf(s, w.z, a.z);
    a.w = fmaf(s, w.w, a.w);
}

// ---------------------------------------------------------------------------
// prep: grid 179 x 256
//   blocks  0..49 : v rows (2 per block; closed-form Dirichlet pe; w1 in LDS)
//   block      50 : u (t<128)
//   blocks 51..178: S[b,n] scatter-sum (b = blk-51)
// ---------------------------------------------------------------------------
__global__ __launch_bounds__(256)
void prep_kernel(const float* __restrict__ cad,
                 const float* __restrict__ w_dist,
                 const float* __restrict__ b_dist,
                 const float* __restrict__ w1,
                 const float* __restrict__ b1,
                 float* __restrict__ ws) {
    __shared__ float w1_l[D * D];   // 64 KB (v-blocks only)
    __shared__ float x_l[2][D];     // 99*b_dist + pe, 2 rows
    __shared__ float S_l[NN];       // S-blocks only
    const int blk = blockIdx.x;
    const int t   = threadIdx.x;

    if (blk < NN / 2) {
        // ---- stage w1 (coalesced float4) ----
        for (int i = t; i < D * D / 4; i += 256)
            ((float4*)w1_l)[i] = ((const float4*)w1)[i];

        // ---- pe rows n = 2*blk + half, fold 99*b_dist in ----
        const int half = t >> 7;          // 0 or 1
        const int tl   = t & 127;
        const int n    = 2 * blk + half;
        {
            const int c = tl & 3;
            const int q = tl >> 2;
            const float kf = (float)(4 * q);
            const float L = 9.210340371976184f / 128.0f;   // ln(1e4)/d
            float val;
            if (c == 0) {
                float a = expf(-kf * L);
                val = (float)NN * sinf((float)n * a);
            } else if (c == 1) {
                float a = expf(-kf * L);
                val = (float)NN * cosf((float)n * a);
            } else if (c == 2) {
                // sum_{j=0}^{99} sin(j a) = sin(50a) sin(49.5a) / sin(a/2)
                float a = expf(-(kf + 2.0f) * L);
                val = sinf(50.0f * a) * sinf(49.5f * a) / sinf(0.5f * a);
            } else {
                // sum_{j=0}^{99} cos(|n-j| a) = [sin((n+.5)a)+sin((99.5-n)a)]/(2 sin(a/2))
                float a = expf(-(kf + 3.0f) * L);
                val = (sinf(((float)n + 0.5f) * a) + sinf((99.5f - (float)n) * a))
                      / (2.0f * sinf(0.5f * a));
            }
            x_l[half][tl] = fmaf(99.0f, b_dist[tl], val);
        }
        __syncthreads();

        // ---- v[n,tl] = (x_l[half] . w1[:,tl]) / N + b1[tl] ----
        {
            float acc = 0.f;
            #pragma unroll 4
            for (int dd = 0; dd < D; ++dd)
                acc = fmaf(x_l[half][dd], w1_l[dd * D + tl], acc);
            ws[V_OFF + n * D + tl] = acc * (1.0f / (float)NN) + b1[tl];
        }
    } else if (blk == NN / 2) {
        if (t < D) {
            // ---- u[e] = w_dist @ w1 ----
            float acc = 0.f;
            #pragma unroll 4
            for (int dd = 0; dd < D; ++dd) acc = fmaf(w_dist[dd], w1[dd * D + t], acc);
            ws[U_OFF + t] = acc;
        }
    } else {
        // ---- S'[b,n] = (sum of cad over incident edges)/N ----
        const int b = blk - (NN / 2 + 1);
        if (t < NN) S_l[t] = 0.f;
        __syncthreads();
        const float* cb = cad + b * PP;
        for (int p = t; p < PP; p += 256) {
            float val = cb[p];
            // invert p -> (i,j), i<j, triu row-major
            int i = (int)((199.0f - sqrtf((float)(39601 - 8 * p))) * 0.5f);
            while (i * (199 - i) / 2 > p) --i;
            while ((i + 1) * (198 - i) / 2 <= p) ++i;
            int j = p - i * (199 - i) / 2 + i + 1;
            atomicAdd(&S_l[i], val);
            atomicAdd(&S_l[j], val);
        }
        __syncthreads();
        if (t < NN) ws[S_OFF + b * NN + t] = S_l[t] * (1.0f / (float)NN);
    }
}

// ---------------------------------------------------------------------------
// gemm2: grid (4 chunks, 128 b) x 256. Each block: 32 rows x 128 e.
//   h1 built in LDS from (S,u,v). w2 read DIRECTLY from global (L2-resident,
//   shared read-only across 512 blocks; coalesced 512B/wave broadcast reads)
//   -> LDS only 16 KB -> many blocks/CU -> latency hidden by waves.
//   Block-local pool partial -> plain store to part[chunk][b][:] (disjoint).
// ---------------------------------------------------------------------------
__global__ __launch_bounds__(256)
void gemm2_kernel(const float* __restrict__ w2,      // [D,D]
                  const float* __restrict__ b2,      // [D]
                  float* __restrict__ ws) {
    const int chunk = blockIdx.x;        // 0..3
    const int b     = blockIdx.y;        // 0..127
    const int tid   = threadIdx.x;
    const int base  = chunk * 32;

    __shared__ float h1_l[32 * D];       // 16 KB, reused as red[8][D]

    const float* u_g    = ws + U_OFF;
    const float* v_g    = ws + V_OFF;
    const float* S_g    = ws + S_OFF + b * NN;
    float*       part_g = ws + PART_OFF + (chunk * BB + b) * D;

    // stage h1 rows base..base+31
    {
        const int dd0 = (tid & 31) * 4;
        const int r0  = tid >> 5;
        const float4 uv = *(const float4*)(u_g + dd0);
        #pragma unroll
        for (int k = 0; k < 4; ++k) {
            const int lr = r0 + k * 8;
            const int g  = base + lr;
            float4 h = {0.f, 0.f, 0.f, 0.f};
            if (g < NN) {
                const float s = S_g[g];
                const float4 vv = *(const float4*)(v_g + g * D + dd0);
                h.x = fmaxf(fmaf(s, uv.x, vv.x), 0.f);
                h.y = fmaxf(fmaf(s, uv.y, vv.y), 0.f);
                h.z = fmaxf(fmaf(s, uv.z, vv.z), 0.f);
                h.w = fmaxf(fmaf(s, uv.w, vv.w), 0.f);
            }
            *(float4*)(h1_l + lr * D + dd0) = h;
        }
    }
    __syncthreads();

    // GEMM: thread (slot=tid>>5, eq=tid&31): rows slot*4.., cols eq*4..
    const int eq   = tid & 31;
    const int slot = tid >> 5;
    const int e0   = eq * 4;
    const int lr0  = slot * 4;
    const int g0   = base + lr0;

    float4 pool = {0.f, 0.f, 0.f, 0.f};
    if (g0 < NN) {
        const float4 b2v = *(const float4*)(b2 + e0);
        float4 acc0 = {0,0,0,0}, acc1 = {0,0,0,0};
        float4 acc2 = {0,0,0,0}, acc3 = {0,0,0,0};
        #pragma unroll 4
        for (int dd = 0; dd < D; dd += 4) {
            const float4 w0  = *(const float4*)&w2[(dd + 0) * D + e0];
            const float4 w1v = *(const float4*)&w2[(dd + 1) * D + e0];
            const float4 w2v = *(const float4*)&w2[(dd + 2) * D + e0];
            const float4 w3v = *(const float4*)&w2[(dd + 3) * D + e0];
            float4 h;
            h = *(const float4*)&h1_l[(lr0 + 0) * D + dd];
            fma4(acc0, h.x, w0); fma4(acc0, h.y, w1v); fma4(acc0, h.z, w2v); fma4(acc0, h.w, w3v);
            h = *(const float4*)&h1_l[(lr0 + 1) * D + dd];
            fma4(acc1, h.x, w0); fma4(acc1, h.y, w1v); fma4(acc1, h.z, w2v); fma4(acc1, h.w, w3v);
            h = *(const float4*)&h1_l[(lr0 + 2) * D + dd];
            fma4(acc2, h.x, w0); fma4(acc2, h.y, w1v); fma4(acc2, h.z, w2v); fma4(acc2, h.w, w3v);
            h = *(const float4*)&h1_l[(lr0 + 3) * D + dd];
            fma4(acc3, h.x, w0); fma4(acc3, h.y, w1v); fma4(acc3, h.z, w2v); fma4(acc3, h.w, w3v);
        }
        if (g0 + 0 < NN) {
            pool.x += fmaxf(acc0.x + b2v.x, 0.f); pool.y += fmaxf(acc0.y + b2v.y, 0.f);
            pool.z += fmaxf(acc0.z + b2v.z, 0.f); pool.w += fmaxf(acc0.w + b2v.w, 0.f);
        }
        if (g0 + 1 < NN) {
            pool.x += fmaxf(acc1.x + b2v.x, 0.f); pool.y += fmaxf(acc1.y + b2v.y, 0.f);
            pool.z += fmaxf(acc1.z + b2v.z, 0.f); pool.w += fmaxf(acc1.w + b2v.w, 0.f);
        }
        if (g0 + 2 < NN) {
            pool.x += fmaxf(acc2.x + b2v.x, 0.f); pool.y += fmaxf(acc2.y + b2v.y, 0.f);
            pool.z += fmaxf(acc2.z + b2v.z, 0.f); pool.w += fmaxf(acc2.w + b2v.w, 0.f);
        }
        if (g0 + 3 < NN) {
            pool.x += fmaxf(acc3.x + b2v.x, 0.f); pool.y += fmaxf(acc3.y + b2v.y, 0.f);
            pool.z += fmaxf(acc3.z + b2v.z, 0.f); pool.w += fmaxf(acc3.w + b2v.w, 0.f);
        }
    }
    __syncthreads();   // done reading h1_l -> safe to reuse as reduce buffer

    // reduce pool across 8 slots (reuse h1_l as red[8][D]), store partial
    *(float4*)(h1_l + slot * D + e0) = pool;
    __syncthreads();
    if (tid < D) {
        float s = 0.f;
        #pragma unroll
        for (int sl = 0; sl < 8; ++sl) s += h1_l[sl * D + tid];
        part_g[tid] = s;
    }
}

// ---------------------------------------------------------------------------
// head: grid 128 x 64.  sum 4 partials -> /N -> relu(@wo1+bo1) -> @wo2+bo2
// ---------------------------------------------------------------------------
__global__ __launch_bounds__(64)
void head_kernel(const float* __restrict__ wo1,     // [D,64]
                 const float* __restrict__ bo1,     // [64]
                 const float* __restrict__ wo2,     // [64,2]
                 const float* __restrict__ bo2,     // [2]
                 const float* __restrict__ ws,
                 float* __restrict__ out) {         // [B,2]
    const int b = blockIdx.x;
    const int t = threadIdx.x;
    __shared__ float pooled_l[D];
    __shared__ float z_l[64];

    const float* part = ws + PART_OFF + b * D;
    #pragma unroll
    for (int r = 0; r < 2; ++r) {
        const int e = t + r * 64;
        float s = 0.f;
        #pragma unroll
        for (int c = 0; c < 4; ++c) s += part[c * BB * D + e];
        pooled_l[e] = s * (1.0f / (float)NN);
    }
    __syncthreads();

    float acc = bo1[t];
    #pragma unroll 4
    for (int e = 0; e < D; ++e)
        acc = fmaf(pooled_l[e], wo1[e * 64 + t], acc);
    z_l[t] = fmaxf(acc, 0.f);
    __syncthreads();

    if (t < 2) {
        float o = bo2[t];
        #pragma unroll 4
        for (int k = 0; k < 64; ++k) o = fmaf(z_l[k], wo2[k * 2 + t], o);
        out[b * 2 + t] = o;
    }
}

extern "C" void kernel_launch(void* const* d_in, const int* in_sizes, int n_in,
                              void* d_out, int out_size, void* d_ws, size_t ws_size,
                              hipStream_t stream) {
    const float* cad    = (const float*)d_in[0];
    const float* w_dist = (const float*)d_in[1];
    const float* b_dist = (const float*)d_in[2];
    const float* w1     = (const float*)d_in[3];
    const float* b1     = (const float*)d_in[4];
    const float* w2     = (const float*)d_in[5];
    const float* b2     = (const float*)d_in[6];
    const float* wo1    = (const float*)d_in[7];
    const float* bo1    = (const float*)d_in[8];
    const float* wo2    = (const float*)d_in[9];
    const float* bo2    = (const float*)d_in[10];
    float* ws  = (float*)d_ws;
    float* out = (float*)d_out;

    prep_kernel<<<dim3(NN / 2 + 1 + BB), dim3(256), 0, stream>>>(cad, w_dist, b_dist, w1, b1, ws);
    gemm2_kernel<<<dim3(4, BB), dim3(256), 0, stream>>>(w2, b2, ws);
    head_kernel<<<dim3(BB), dim3(64), 0, stream>>>(wo1, bo1, wo2, bo2, ws, out);
}

// Round 13
// 113.252 us; speedup vs baseline: 1.0741x; 1.0741x over previous
//
#include <hip/hip_runtime.h>

#define NN 100     // N nodes
#define D  128     // d_model
#define BB 128     // batch
#define PP 4950    // pairs

// ws float offsets
#define U_OFF    0
#define V_OFF    (D)                    // 128
#define S_OFF    (V_OFF + NN * D)       // 12928
#define PART_OFF (S_OFF + BB * NN)      // 25728; part[4][BB][D]

__device__ inline void fma4(float4& a, float s, const float4& w) {
    a.x = fmaf(s, w.x, a.x);
    a.y = fmaf(s, w.y, a.y);
    a.z = fmaf(s, w.z, a.z);
    a.w = fmaf(s, w.w, a.w);
}

// ---------------------------------------------------------------------------
// prep: grid 179 x 256
//   blocks  0..49 : v rows (2 per block; closed-form Dirichlet pe; w1 in LDS)
//   block      50 : u (t<128)
//   blocks 51..178: S[b,n] scatter-sum (b = blk-51)
// ---------------------------------------------------------------------------
__global__ __launch_bounds__(256)
void prep_kernel(const float* __restrict__ cad,
                 const float* __restrict__ w_dist,
                 const float* __restrict__ b_dist,
                 const float* __restrict__ w1,
                 const float* __restrict__ b1,
                 float* __restrict__ ws) {
    __shared__ float w1_l[D * D];   // 64 KB (v-blocks only)
    __shared__ float x_l[2][D];     // 99*b_dist + pe, 2 rows
    __shared__ float S_l[NN];       // S-blocks only
    const int blk = blockIdx.x;
    const int t   = threadIdx.x;

    if (blk < NN / 2) {
        // ---- stage w1 (coalesced float4) ----
        for (int i = t; i < D * D / 4; i += 256)
            ((float4*)w1_l)[i] = ((const float4*)w1)[i];

        // ---- pe rows n = 2*blk + half, fold 99*b_dist in ----
        const int half = t >> 7;          // 0 or 1
        const int tl   = t & 127;
        const int n    = 2 * blk + half;
        {
            const int c = tl & 3;
            const int q = tl >> 2;
            const float kf = (float)(4 * q);
            const float L = 9.210340371976184f / 128.0f;   // ln(1e4)/d
            float val;
            if (c == 0) {
                float a = expf(-kf * L);
                val = (float)NN * sinf((float)n * a);
            } else if (c == 1) {
                float a = expf(-kf * L);
                val = (float)NN * cosf((float)n * a);
            } else if (c == 2) {
                // sum_{j=0}^{99} sin(j a) = sin(50a) sin(49.5a) / sin(a/2)
                float a = expf(-(kf + 2.0f) * L);
                val = sinf(50.0f * a) * sinf(49.5f * a) / sinf(0.5f * a);
            } else {
                // sum_{j=0}^{99} cos(|n-j| a) = [sin((n+.5)a)+sin((99.5-n)a)]/(2 sin(a/2))
                float a = expf(-(kf + 3.0f) * L);
                val = (sinf(((float)n + 0.5f) * a) + sinf((99.5f - (float)n) * a))
                      / (2.0f * sinf(0.5f * a));
            }
            x_l[half][tl] = fmaf(99.0f, b_dist[tl], val);
        }
        __syncthreads();

        // ---- v[n,tl] = (x_l[half] . w1[:,tl]) / N + b1[tl] ----
        {
            float acc = 0.f;
            #pragma unroll 4
            for (int dd = 0; dd < D; ++dd)
                acc = fmaf(x_l[half][dd], w1_l[dd * D + tl], acc);
            ws[V_OFF + n * D + tl] = acc * (1.0f / (float)NN) + b1[tl];
        }
    } else if (blk == NN / 2) {
        if (t < D) {
            // ---- u[e] = w_dist @ w1 ----
            float acc = 0.f;
            #pragma unroll 4
            for (int dd = 0; dd < D; ++dd) acc = fmaf(w_dist[dd], w1[dd * D + t], acc);
            ws[U_OFF + t] = acc;
        }
    } else {
        // ---- S'[b,n] = (sum of cad over incident edges)/N ----
        const int b = blk - (NN / 2 + 1);
        if (t < NN) S_l[t] = 0.f;
        __syncthreads();
        const float* cb = cad + b * PP;
        for (int p = t; p < PP; p += 256) {
            float val = cb[p];
            // invert p -> (i,j), i<j, triu row-major
            int i = (int)((199.0f - sqrtf((float)(39601 - 8 * p))) * 0.5f);
            while (i * (199 - i) / 2 > p) --i;
            while ((i + 1) * (198 - i) / 2 <= p) ++i;
            int j = p - i * (199 - i) / 2 + i + 1;
            atomicAdd(&S_l[i], val);
            atomicAdd(&S_l[j], val);
        }
        __syncthreads();
        if (t < NN) ws[S_OFF + b * NN + t] = S_l[t] * (1.0f / (float)NN);
    }
}

// ---------------------------------------------------------------------------
// gemm2: grid (4 chunks, 128 b) x 256. Each block: 32 rows x 128 e.
//   h1 built in LDS from (S,u,v); w2 staged in LDS (64 KB; L2-direct variant
//   measured +8.3 us in round 12 — keep the staging).
//   4x4 register tile, slot=tid>>5 (half-wave broadcast h-reads: conflict-free).
//   Block-local pool partial -> plain store to part[chunk][b][:] (disjoint).
// LDS: 64K (w2) + 16K (h1, reused as reduce) -> 2 blocks/CU.
// ---------------------------------------------------------------------------
__global__ __launch_bounds__(256)
void gemm2_kernel(const float* __restrict__ w2,      // [D,D]
                  const float* __restrict__ b2,      // [D]
                  float* __restrict__ ws) {
    const int chunk = blockIdx.x;        // 0..3
    const int b     = blockIdx.y;        // 0..127
    const int tid   = threadIdx.x;
    const int base  = chunk * 32;

    __shared__ float w2_l[D * D];        // 64 KB [d][e]
    __shared__ float h1_l[32 * D];       // 16 KB, reused as red[8][D]

    const float* u_g    = ws + U_OFF;
    const float* v_g    = ws + V_OFF;
    const float* S_g    = ws + S_OFF + b * NN;
    float*       part_g = ws + PART_OFF + (chunk * BB + b) * D;

    // stage w2
    for (int i = tid; i < D * D / 4; i += 256)
        ((float4*)w2_l)[i] = ((const float4*)w2)[i];

    // stage h1 rows base..base+31
    {
        const int dd0 = (tid & 31) * 4;
        const int r0  = tid >> 5;
        const float4 uv = *(const float4*)(u_g + dd0);
        #pragma unroll
        for (int k = 0; k < 4; ++k) {
            const int lr = r0 + k * 8;
            const int g  = base + lr;
            float4 h = {0.f, 0.f, 0.f, 0.f};
            if (g < NN) {
                const float s = S_g[g];
                const float4 vv = *(const float4*)(v_g + g * D + dd0);
                h.x = fmaxf(fmaf(s, uv.x, vv.x), 0.f);
                h.y = fmaxf(fmaf(s, uv.y, vv.y), 0.f);
                h.z = fmaxf(fmaf(s, uv.z, vv.z), 0.f);
                h.w = fmaxf(fmaf(s, uv.w, vv.w), 0.f);
            }
            *(float4*)(h1_l + lr * D + dd0) = h;
        }
    }
    __syncthreads();

    // GEMM: thread (slot=tid>>5, eq=tid&31): rows slot*4.., cols eq*4..
    const int eq   = tid & 31;
    const int slot = tid >> 5;
    const int e0   = eq * 4;
    const int lr0  = slot * 4;
    const int g0   = base + lr0;

    float4 pool = {0.f, 0.f, 0.f, 0.f};
    if (g0 < NN) {
        const float4 b2v = *(const float4*)(b2 + e0);
        float4 acc0 = {0,0,0,0}, acc1 = {0,0,0,0};
        float4 acc2 = {0,0,0,0}, acc3 = {0,0,0,0};
        #pragma unroll 4
        for (int dd = 0; dd < D; dd += 4) {
            const float4 w0  = *(const float4*)&w2_l[(dd + 0) * D + e0];
            const float4 w1v = *(const float4*)&w2_l[(dd + 1) * D + e0];
            const float4 w2v = *(const float4*)&w2_l[(dd + 2) * D + e0];
            const float4 w3v = *(const float4*)&w2_l[(dd + 3) * D + e0];
            float4 h;
            h = *(const float4*)&h1_l[(lr0 + 0) * D + dd];
            fma4(acc0, h.x, w0); fma4(acc0, h.y, w1v); fma4(acc0, h.z, w2v); fma4(acc0, h.w, w3v);
            h = *(const float4*)&h1_l[(lr0 + 1) * D + dd];
            fma4(acc1, h.x, w0); fma4(acc1, h.y, w1v); fma4(acc1, h.z, w2v); fma4(acc1, h.w, w3v);
            h = *(const float4*)&h1_l[(lr0 + 2) * D + dd];
            fma4(acc2, h.x, w0); fma4(acc2, h.y, w1v); fma4(acc2, h.z, w2v); fma4(acc2, h.w, w3v);
            h = *(const float4*)&h1_l[(lr0 + 3) * D + dd];
            fma4(acc3, h.x, w0); fma4(acc3, h.y, w1v); fma4(acc3, h.z, w2v); fma4(acc3, h.w, w3v);
        }
        if (g0 + 0 < NN) {
            pool.x += fmaxf(acc0.x + b2v.x, 0.f); pool.y += fmaxf(acc0.y + b2v.y, 0.f);
            pool.z += fmaxf(acc0.z + b2v.z, 0.f); pool.w += fmaxf(acc0.w + b2v.w, 0.f);
        }
        if (g0 + 1 < NN) {
            pool.x += fmaxf(acc1.x + b2v.x, 0.f); pool.y += fmaxf(acc1.y + b2v.y, 0.f);
            pool.z += fmaxf(acc1.z + b2v.z, 0.f); pool.w += fmaxf(acc1.w + b2v.w, 0.f);
        }
        if (g0 + 2 < NN) {
            pool.x += fmaxf(acc2.x + b2v.x, 0.f); pool.y += fmaxf(acc2.y + b2v.y, 0.f);
            pool.z += fmaxf(acc2.z + b2v.z, 0.f); pool.w += fmaxf(acc2.w + b2v.w, 0.f);
        }
        if (g0 + 3 < NN) {
            pool.x += fmaxf(acc3.x + b2v.x, 0.f); pool.y += fmaxf(acc3.y + b2v.y, 0.f);
            pool.z += fmaxf(acc3.z + b2v.z, 0.f); pool.w += fmaxf(acc3.w + b2v.w, 0.f);
        }
    }
    __syncthreads();   // done reading h1_l -> safe to reuse as reduce buffer

    // reduce pool across 8 slots (reuse h1_l as red[8][D]), store partial
    *(float4*)(h1_l + slot * D + e0) = pool;
    __syncthreads();
    if (tid < D) {
        float s = 0.f;
        #pragma unroll
        for (int sl = 0; sl < 8; ++sl) s += h1_l[sl * D + tid];
        part_g[tid] = s;
    }
}

// ---------------------------------------------------------------------------
// head: grid 128 x 64.  sum 4 partials -> /N -> relu(@wo1+bo1) -> @wo2+bo2
// ---------------------------------------------------------------------------
__global__ __launch_bounds__(64)
void head_kernel(const float* __restrict__ wo1,     // [D,64]
                 const float* __restrict__ bo1,     // [64]
                 const float* __restrict__ wo2,     // [64,2]
                 const float* __restrict__ bo2,     // [2]
                 const float* __restrict__ ws,
                 float* __restrict__ out) {         // [B,2]
    const int b = blockIdx.x;
    const int t = threadIdx.x;
    __shared__ float pooled_l[D];
    __shared__ float z_l[64];

    const float* part = ws + PART_OFF + b * D;
    #pragma unroll
    for (int r = 0; r < 2; ++r) {
        const int e = t + r * 64;
        float s = 0.f;
        #pragma unroll
        for (int c = 0; c < 4; ++c) s += part[c * BB * D + e];
        pooled_l[e] = s * (1.0f / (float)NN);
    }
    __syncthreads();

    float acc = bo1[t];
    #pragma unroll 4
    for (int e = 0; e < D; ++e)
        acc = fmaf(pooled_l[e], wo1[e * 64 + t], acc);
    z_l[t] = fmaxf(acc, 0.f);
    __syncthreads();

    if (t < 2) {
        float o = bo2[t];
        #pragma unroll 4
        for (int k = 0; k < 64; ++k) o = fmaf(z_l[k], wo2[k * 2 + t], o);
        out[b * 2 + t] = o;
    }
}

extern "C" void kernel_launch(void* const* d_in, const int* in_sizes, int n_in,
                              void* d_out, int out_size, void* d_ws, size_t ws_size,
                              hipStream_t stream) {
    const float* cad    = (const float*)d_in[0];
    const float* w_dist = (const float*)d_in[1];
    const float* b_dist = (const float*)d_in[2];
    const float* w1     = (const float*)d_in[3];
    const float* b1     = (const float*)d_in[4];
    const float* w2     = (const float*)d_in[5];
    const float* b2     = (const float*)d_in[6];
    const float* wo1    = (const float*)d_in[7];
    const float* bo1    = (const float*)d_in[8];
    const float* wo2    = (const float*)d_in[9];
    const float* bo2    = (const float*)d_in[10];
    float* ws  = (float*)d_ws;
    float* out = (float*)d_out;

    prep_kernel<<<dim3(NN / 2 + 1 + BB), dim3(256), 0, stream>>>(cad, w_dist, b_dist, w1, b1, ws);
    gemm2_kernel<<<dim3(4, BB), dim3(256), 0, stream>>>(w2, b2, ws);
    head_kernel<<<dim3(BB), dim3(64), 0, stream>>>(wo1, bo1, wo2, bo2, ws, out);
}